// Round 2
// 493.635 us; speedup vs baseline: 1.5399x; 1.5399x over previous
//
#include <hip/hip_runtime.h>
#include <hip/hip_bf16.h>
#include <math.h>

// Problem constants
#define BB 2
#define TT 1024
#define CC 1024
#define HH 16
#define DD 64
#define EE 16
#define II 256
#define NN (BB*TT)          // 2048 tokens
#define EPSLN 1e-5f
#define LDA 72              // bf16 LDS row stride: 144B rows, 16B-aligned

typedef __attribute__((ext_vector_type(8))) short short8;
typedef __attribute__((ext_vector_type(4))) short s16x4;
typedef __attribute__((ext_vector_type(4))) float f32x4;

__device__ inline void splitbf(float x, short& hi, short& lo) {
    __hip_bfloat16 h = __float2bfloat16(x);
    float hf = __bfloat162float(h);
    __hip_bfloat16 l = __float2bfloat16(x - hf);
    hi = *(short*)&h;
    lo = *(short*)&l;
}

// ---------------------------------------------------------------------------
// LayerNorm: one block per row of 1024.
// Optional outputs: fp32, single bf16, split bf16 hi/lo.
// ---------------------------------------------------------------------------
__global__ __launch_bounds__(256) void ln_kernel(const float* __restrict__ x,
                                                 const float* __restrict__ g,
                                                 const float* __restrict__ bta,
                                                 float* __restrict__ out,
                                                 __hip_bfloat16* __restrict__ outb,
                                                 __hip_bfloat16* __restrict__ outh,
                                                 __hip_bfloat16* __restrict__ outl) {
    const int row = blockIdx.x, tid = threadIdx.x;
    __shared__ float r1[256], r2[256];
    const float* xr = x + (long)row * CC;
    float4 xv = ((const float4*)xr)[tid];
    float s  = xv.x + xv.y + xv.z + xv.w;
    float q2 = xv.x*xv.x + xv.y*xv.y + xv.z*xv.z + xv.w*xv.w;
    r1[tid] = s; r2[tid] = q2; __syncthreads();
    for (int st = 128; st > 0; st >>= 1) {
        if (tid < st) { r1[tid] += r1[tid+st]; r2[tid] += r2[tid+st]; }
        __syncthreads();
    }
    const float mu  = r1[0] * (1.f/CC);
    const float var = r2[0] * (1.f/CC) - mu*mu;
    const float rs  = rsqrtf(var + EPSLN);
    float4 gv = ((const float4*)g)[tid];
    float4 bv = ((const float4*)bta)[tid];
    float4 ov;
    ov.x = (xv.x-mu)*rs*gv.x + bv.x;
    ov.y = (xv.y-mu)*rs*gv.y + bv.y;
    ov.z = (xv.z-mu)*rs*gv.z + bv.z;
    ov.w = (xv.w-mu)*rs*gv.w + bv.w;
    if (out)
        ((float4*)(out + (long)row * CC))[tid] = ov;
    if (outb) {
        __hip_bfloat16* p = outb + (long)row * CC + tid*4;
        p[0] = __float2bfloat16(ov.x); p[1] = __float2bfloat16(ov.y);
        p[2] = __float2bfloat16(ov.z); p[3] = __float2bfloat16(ov.w);
    }
    if (outh) {
        float xs[4] = {ov.x, ov.y, ov.z, ov.w};
        s16x4 hv, lv;
        #pragma unroll
        for (int j = 0; j < 4; j++) { short h,l; splitbf(xs[j], h, l); hv[j]=h; lv[j]=l; }
        *(s16x4*)(outh + (long)row * CC + tid*4) = hv;
        *(s16x4*)(outl + (long)row * CC + tid*4) = lv;
    }
}

// ---------------------------------------------------------------------------
// One-shot weight prep: W[K][N] fp32 -> Wt[N][K] bf16 hi + lo (bf16x3 split).
// ---------------------------------------------------------------------------
__global__ __launch_bounds__(256) void transpose_split(const float* __restrict__ W,
                                                       __hip_bfloat16* __restrict__ Wth,
                                                       __hip_bfloat16* __restrict__ Wtl,
                                                       int K, int N) {
    const int n0 = blockIdx.x * 32, k0 = blockIdx.y * 32;
    __shared__ float t[32][33];
    const int tx = threadIdx.x & 31, ty = threadIdx.x >> 5;
    #pragma unroll
    for (int i = 0; i < 4; i++)
        t[ty + i*8][tx] = W[(long)(k0 + ty + i*8)*N + n0 + tx];
    __syncthreads();
    #pragma unroll
    for (int i = 0; i < 4; i++) {
        float v = t[tx][ty + i*8];
        short h, l; splitbf(v, h, l);
        *(short*)&Wth[(long)(n0 + ty + i*8)*K + k0 + tx] = h;
        *(short*)&Wtl[(long)(n0 + ty + i*8)*K + k0 + tx] = l;
    }
}

// ---------------------------------------------------------------------------
// fp32-accurate MFMA GEMM via bf16x3 split (AhBh + AhBl + AlBh) with
// PRE-SPLIT inputs: A = (Ah,Al)[M][K] bf16, B = (Bth,Btl)[z][N][K] bf16.
// All LDS staging is contiguous short8 -> no bank-conflict scatter.
// Tile 64Mx128N, BK=32, 4 waves. z indexes weight slot + C output slab.
// EPI: 0 = plain, 1 = +resid
// ---------------------------------------------------------------------------
template<int EPI>
__global__ __launch_bounds__(256, 2) void gemm_split(
        const __hip_bfloat16* __restrict__ Ah,
        const __hip_bfloat16* __restrict__ Al,
        const __hip_bfloat16* __restrict__ Bh_base,
        const __hip_bfloat16* __restrict__ Bl_base,
        float* __restrict__ C_base,
        int M, int N, int K,
        const float* __restrict__ resid) {
    __shared__ __hip_bfloat16 Ash[64][40], Asl[64][40];
    __shared__ __hip_bfloat16 Bsh[128][40], Bsl[128][40];
    const int z = blockIdx.z;
    const __hip_bfloat16* Bth = Bh_base + (long)z * N * K;
    const __hip_bfloat16* Btl = Bl_base + (long)z * N * K;
    float* Cp = C_base + (long)z * M * N;
    const int n0 = blockIdx.x * 128, m0 = blockIdx.y * 64;
    const int tid = threadIdx.x;
    const int wave = tid >> 6, lane = tid & 63;
    const int wm = (wave >> 1) * 32, wn = (wave & 1) * 64;
    const int l15 = lane & 15, quad = lane >> 4;

    f32x4 acc[2][4] = {};

    for (int k0 = 0; k0 < K; k0 += 32) {
        {   // A tile: 64 rows x 32 k, contiguous short8 per thread
            const int r = tid >> 2, kg = (tid & 3) * 8;
            *(short8*)&Ash[r][kg] = *(const short8*)(Ah + (long)(m0 + r)*K + k0 + kg);
            *(short8*)&Asl[r][kg] = *(const short8*)(Al + (long)(m0 + r)*K + k0 + kg);
        }
        #pragma unroll
        for (int it = 0; it < 2; it++) {   // B tile: 128 rows x 32 k
            const int idx = tid + it*256;
            const int r = idx >> 2, kg = (idx & 3) * 8;
            *(short8*)&Bsh[r][kg] = *(const short8*)(Bth + (long)(n0 + r)*K + k0 + kg);
            *(short8*)&Bsl[r][kg] = *(const short8*)(Btl + (long)(n0 + r)*K + k0 + kg);
        }
        __syncthreads();
        short8 ah[2], al[2], bh[4], bl[4];
        #pragma unroll
        for (int mi = 0; mi < 2; mi++) {
            ah[mi] = *(const short8*)&Ash[wm + mi*16 + l15][quad*8];
            al[mi] = *(const short8*)&Asl[wm + mi*16 + l15][quad*8];
        }
        #pragma unroll
        for (int ni = 0; ni < 4; ni++) {
            bh[ni] = *(const short8*)&Bsh[wn + ni*16 + l15][quad*8];
            bl[ni] = *(const short8*)&Bsl[wn + ni*16 + l15][quad*8];
        }
        #pragma unroll
        for (int mi = 0; mi < 2; mi++)
            #pragma unroll
            for (int ni = 0; ni < 4; ni++) {
                acc[mi][ni] = __builtin_amdgcn_mfma_f32_16x16x32_bf16(ah[mi], bh[ni], acc[mi][ni], 0,0,0);
                acc[mi][ni] = __builtin_amdgcn_mfma_f32_16x16x32_bf16(ah[mi], bl[ni], acc[mi][ni], 0,0,0);
                acc[mi][ni] = __builtin_amdgcn_mfma_f32_16x16x32_bf16(al[mi], bh[ni], acc[mi][ni], 0,0,0);
            }
        __syncthreads();
    }

    #pragma unroll
    for (int mi = 0; mi < 2; mi++)
        #pragma unroll
        for (int r = 0; r < 4; r++) {
            const int row = m0 + wm + mi*16 + quad*4 + r;
            #pragma unroll
            for (int ni = 0; ni < 4; ni++) {
                const int col = n0 + wn + ni*16 + l15;
                float val = acc[mi][ni][r];
                if (EPI == 1) val += resid[(long)row*N + col];
                Cp[(long)row*N + col] = val;
            }
        }
}

// ---------------------------------------------------------------------------
// bf16 MFMA GEMM (expert path): C = A[M,K] * Bt[N,K]^T, batched over z.
// EPI: 0 = exact gelu -> bf16 out; 1 = *mask -> fp32 strided out
// ---------------------------------------------------------------------------
template<int EPI>
__global__ __launch_bounds__(256) void gemm_mfma(
        const __hip_bfloat16* __restrict__ A, long sAe,
        const __hip_bfloat16* __restrict__ Bt, long sBe,
        void* __restrict__ Cp, long sCe, int ldc,
        int M, int N, int K,
        const float* __restrict__ mask) {
    constexpr int LDK = 40;
    __shared__ __hip_bfloat16 As[128][LDK];
    __shared__ __hip_bfloat16 Bs[128][LDK];
    const int e = blockIdx.z;
    A  += (long)e * sAe;
    Bt += (long)e * sBe;
    const int n0 = blockIdx.x * 128, m0 = blockIdx.y * 128;
    const int tid = threadIdx.x;
    const int wave = tid >> 6, lane = tid & 63;
    const int wm = (wave >> 1) * 64, wn = (wave & 1) * 64;
    const int l15 = lane & 15, quad = lane >> 4;

    f32x4 acc[4][4] = {};

    for (int k0 = 0; k0 < K; k0 += 32) {
        #pragma unroll
        for (int it = 0; it < 2; it++) {
            int idx = tid + it*256;
            int r = idx >> 2, kg = idx & 3;
            short8 av = *(const short8*)(A  + (long)(m0 + r)*K + k0 + kg*8);
            short8 bv = *(const short8*)(Bt + (long)(n0 + r)*K + k0 + kg*8);
            *(short8*)&As[r][kg*8] = av;
            *(short8*)&Bs[r][kg*8] = bv;
        }
        __syncthreads();
        short8 af[4], bff[4];
        #pragma unroll
        for (int i = 0; i < 4; i++) {
            af[i]  = *(const short8*)&As[wm + i*16 + l15][quad*8];
            bff[i] = *(const short8*)&Bs[wn + i*16 + l15][quad*8];
        }
        #pragma unroll
        for (int mi = 0; mi < 4; mi++)
            #pragma unroll
            for (int ni = 0; ni < 4; ni++)
                acc[mi][ni] = __builtin_amdgcn_mfma_f32_16x16x32_bf16(
                                  af[mi], bff[ni], acc[mi][ni], 0, 0, 0);
        __syncthreads();
    }

    #pragma unroll
    for (int mi = 0; mi < 4; mi++) {
        #pragma unroll
        for (int r = 0; r < 4; r++) {
            const int row = m0 + wm + mi*16 + quad*4 + r;
            float mv = 0.f;
            if (EPI == 1) mv = mask[(long)row*EE + e];
            #pragma unroll
            for (int ni = 0; ni < 4; ni++) {
                const int col = n0 + wn + ni*16 + l15;
                float val = acc[mi][ni][r];
                if (EPI == 0) {
                    val = 0.5f*val*(1.f + erff(val*0.70710678118f));
                    ((__hip_bfloat16*)Cp)[(long)e*sCe + (long)row*ldc + col] =
                        __float2bfloat16(val);
                } else {
                    ((float*)Cp)[(long)e*sCe + (long)row*ldc + col] = val*mv;
                }
            }
        }
    }
}

// ---------------------------------------------------------------------------
// Tiled fp32 -> bf16 transpose for expert weights.
// ---------------------------------------------------------------------------
__global__ __launch_bounds__(256) void transpose_f2b(const float* __restrict__ W, long sWe,
                                                     __hip_bfloat16* __restrict__ Wt, long sWte,
                                                     int K, int N) {
    const int e = blockIdx.z;
    W  += (long)e * sWe;
    Wt += (long)e * sWte;
    const int n0 = blockIdx.x * 32, k0 = blockIdx.y * 32;
    __shared__ float t[32][33];
    const int tx = threadIdx.x & 31, ty = threadIdx.x >> 5;
    #pragma unroll
    for (int i = 0; i < 4; i++)
        t[ty + i*8][tx] = W[(long)(k0 + ty + i*8)*N + n0 + tx];
    __syncthreads();
    #pragma unroll
    for (int i = 0; i < 4; i++)
        Wt[(long)(n0 + ty + i*8)*K + k0 + tx] = __float2bfloat16(t[tx][ty + i*8]);
}

// ---------------------------------------------------------------------------
// Flash attention with bf16x3 MFMA for QK^T and PV. kt-split for balance.
// Block = (b, h, qt, half). Q A-frags from global (no LDS). K staged split
// [key][d]; V staged transposed split [d][kk]; P overwrites K region
// (C/D -> A layout round-trip). Online softmax in registers via width-16
// shuffles (C/D rows = quad*4+reg). Unnormalized O + (m,l) partials out.
// ---------------------------------------------------------------------------
__global__ __launch_bounds__(256, 4) void attn_split(const float* __restrict__ q,
                                                     const float* __restrict__ k,
                                                     const float* __restrict__ v,
                                                     float* __restrict__ Opart,
                                                     float* __restrict__ mpart,
                                                     float* __restrict__ lpart) {
    __shared__ __hip_bfloat16 KPh[64][LDA], KPl[64][LDA];   // K, then P
    __shared__ __hip_bfloat16 Vth[64][LDA], Vtl[64][LDA];   // V^T [d][kk]

    const int bx = blockIdx.x;                 // 0..31, heavy qt first
    const int qt = 15 - (bx >> 1), half = bx & 1;
    const int h = blockIdx.y, b = blockIdx.z;
    const int tid = threadIdx.x;
    const int wave = tid >> 6, lane = tid & 63;
    const int l15 = lane & 15, quad = lane >> 4;
    const int wm = wave * 16;                  // wave's 16 q-rows in the 64-tile
    const long base = (long)b * TT * CC + (long)h * DD;
    const int pidx = ((b*HH + h)*16 + qt)*2 + half;
    float* Op = Opart + (long)pidx * 4096;

    const int n_kt = qt + 1, mid_kt = (n_kt + 1) >> 1;
    const int kt_lo = half ? mid_kt : 0;
    const int kt_hi = half ? n_kt   : mid_kt;

    if (kt_lo >= kt_hi) {      // empty half (qt=0): neutral partials
        for (int i = tid; i < 64*64; i += 256) Op[i] = 0.f;
        if (tid < 64) { mpart[(long)pidx*64 + tid] = -1e30f; lpart[(long)pidx*64 + tid] = 0.f; }
        return;
    }

    // Q A-fragments from global, split: row = qt*64 + wm + l15, k = kc*32+quad*8
    short8 qh[2], ql[2];
    {
        const float* qrow = q + base + (long)(qt*64 + wm + l15)*CC;
        #pragma unroll
        for (int kc = 0; kc < 2; kc++) {
            const float* p = qrow + kc*32 + quad*8;
            float4 x0 = *(const float4*)p, x1 = *(const float4*)(p + 4);
            float xs[8] = {x0.x,x0.y,x0.z,x0.w,x1.x,x1.y,x1.z,x1.w};
            #pragma unroll
            for (int j = 0; j < 8; j++) { short hh,ll; splitbf(xs[j],hh,ll); qh[kc][j]=hh; ql[kc][j]=ll; }
        }
    }

    f32x4 oacc[4] = {};            // 4 d-tiles, rows = quad*4+reg
    float m_run[4], l_run[4];
    #pragma unroll
    for (int r = 0; r < 4; r++) { m_run[r] = -1e30f; l_run[r] = 0.f; }

    for (int kt = kt_lo; kt < kt_hi; kt++) {
        __syncthreads();           // prev-iter PV reads of KP/Vt done
        // stage K split: [key r][d]
        #pragma unroll
        for (int it = 0; it < 2; it++) {
            int idx = tid + it*256;
            int r = idx >> 3, g = (idx & 7)*8;
            const float* kp = k + base + (long)(kt*64 + r)*CC + g;
            float4 x0 = *(const float4*)kp, x1 = *(const float4*)(kp + 4);
            float xs[8] = {x0.x,x0.y,x0.z,x0.w,x1.x,x1.y,x1.z,x1.w};
            short8 hv, lv;
            #pragma unroll
            for (int j = 0; j < 8; j++) { short hh,ll; splitbf(xs[j],hh,ll); hv[j]=hh; lv[j]=ll; }
            *(short8*)&KPh[r][g] = hv;
            *(short8*)&KPl[r][g] = lv;
        }
        // stage V transposed split: read 8 d at token kk, scatter rows d
        #pragma unroll
        for (int it = 0; it < 2; it++) {
            int idx = tid + it*256;
            int kk = idx >> 3, g = (idx & 7)*8;
            const float* vp = v + base + (long)(kt*64 + kk)*CC + g;
            float4 x0 = *(const float4*)vp, x1 = *(const float4*)(vp + 4);
            float xs[8] = {x0.x,x0.y,x0.z,x0.w,x1.x,x1.y,x1.z,x1.w};
            #pragma unroll
            for (int j = 0; j < 8; j++) {
                short hh,ll; splitbf(xs[j],hh,ll);
                *(short*)&Vth[g+j][kk] = hh;
                *(short*)&Vtl[g+j][kk] = ll;
            }
        }
        __syncthreads();

        // QK^T via MFMA: 4 key-tiles x 2 k-chunks x 3 split terms
        f32x4 s[4] = {};
        #pragma unroll
        for (int nt = 0; nt < 4; nt++)
            #pragma unroll
            for (int kc = 0; kc < 2; kc++) {
                short8 bh = *(const short8*)&KPh[nt*16 + l15][kc*32 + quad*8];
                short8 bl = *(const short8*)&KPl[nt*16 + l15][kc*32 + quad*8];
                s[nt] = __builtin_amdgcn_mfma_f32_16x16x32_bf16(qh[kc], bh, s[nt], 0,0,0);
                s[nt] = __builtin_amdgcn_mfma_f32_16x16x32_bf16(qh[kc], bl, s[nt], 0,0,0);
                s[nt] = __builtin_amdgcn_mfma_f32_16x16x32_bf16(ql[kc], bh, s[nt], 0,0,0);
            }

        // online softmax in regs; row = wm + quad*4 + r, col = nt*16 + l15
        const bool diag = (kt == qt);
        float alpha[4];
        float pr[4][4];
        #pragma unroll
        for (int r = 0; r < 4; r++) {
            const int rowg = wm + quad*4 + r;
            float sv[4], mx = -1e30f;
            #pragma unroll
            for (int nt = 0; nt < 4; nt++) {
                float val = s[nt][r] * 0.125f;
                if (diag && (nt*16 + l15) > rowg) val = -1e30f;
                sv[nt] = val;
                mx = fmaxf(mx, val);
            }
            #pragma unroll
            for (int off = 1; off < 16; off <<= 1) mx = fmaxf(mx, __shfl_xor(mx, off, 16));
            const float mnew = fmaxf(m_run[r], mx);
            alpha[r] = __expf(m_run[r] - mnew);
            float rs = 0.f;
            #pragma unroll
            for (int nt = 0; nt < 4; nt++) {
                float p = __expf(sv[nt] - mnew);
                pr[r][nt] = p;
                rs += p;
            }
            #pragma unroll
            for (int off = 1; off < 16; off <<= 1) rs += __shfl_xor(rs, off, 16);
            l_run[r] = l_run[r]*alpha[r] + rs;
            m_run[r] = mnew;
        }
        __syncthreads();           // all QK reads of KP done -> overwrite as P

        // write P split into KP region: row = wm+quad*4+r, col = nt*16+l15
        #pragma unroll
        for (int r = 0; r < 4; r++)
            #pragma unroll
            for (int nt = 0; nt < 4; nt++) {
                short hh, ll; splitbf(pr[r][nt], hh, ll);
                *(short*)&KPh[wm + quad*4 + r][nt*16 + l15] = hh;
                *(short*)&KPl[wm + quad*4 + r][nt*16 + l15] = ll;
            }
        // no barrier: PV reads only this wave's own 16 P-rows

        // rescale O and accumulate PV via MFMA
        #pragma unroll
        for (int dt = 0; dt < 4; dt++)
            #pragma unroll
            for (int r = 0; r < 4; r++)
                oacc[dt][r] *= alpha[r];
        #pragma unroll
        for (int kc = 0; kc < 2; kc++) {
            short8 ph = *(const short8*)&KPh[wm + l15][kc*32 + quad*8];
            short8 pl = *(const short8*)&KPl[wm + l15][kc*32 + quad*8];
            #pragma unroll
            for (int dt = 0; dt < 4; dt++) {
                short8 vh = *(const short8*)&Vth[dt*16 + l15][kc*32 + quad*8];
                short8 vl = *(const short8*)&Vtl[dt*16 + l15][kc*32 + quad*8];
                oacc[dt] = __builtin_amdgcn_mfma_f32_16x16x32_bf16(ph, vh, oacc[dt], 0,0,0);
                oacc[dt] = __builtin_amdgcn_mfma_f32_16x16x32_bf16(ph, vl, oacc[dt], 0,0,0);
                oacc[dt] = __builtin_amdgcn_mfma_f32_16x16x32_bf16(pl, vh, oacc[dt], 0,0,0);
            }
        }
    }

    // store unnormalized O partial + (m,l)
    #pragma unroll
    for (int dt = 0; dt < 4; dt++)
        #pragma unroll
        for (int r = 0; r < 4; r++)
            Op[(wm + quad*4 + r)*64 + dt*16 + l15] = oacc[dt][r];
    if (l15 == 0) {
        #pragma unroll
        for (int r = 0; r < 4; r++) {
            mpart[(long)pidx*64 + wm + quad*4 + r] = m_run[r];
            lpart[(long)pidx*64 + wm + quad*4 + r] = l_run[r];
        }
    }
}

// ---------------------------------------------------------------------------
// Merge the two kt-half partials -> normalized attention output, emitted as
// pre-split bf16 hi/lo (direct feed for the WO bf16x3 GEMM).
// ---------------------------------------------------------------------------
__global__ __launch_bounds__(256) void attn_merge(const float* __restrict__ Opart,
                                                  const float* __restrict__ mpart,
                                                  const float* __restrict__ lpart,
                                                  __hip_bfloat16* __restrict__ aoh,
                                                  __hip_bfloat16* __restrict__ aol) {
    const int qt = blockIdx.x, h = blockIdx.y, b = blockIdx.z;
    const int pA = ((b*HH + h)*16 + qt)*2, pB = pA + 1;
    const int tid = threadIdx.x;
    const int r = tid >> 2, c0 = (tid & 3) * 16;
    const float mA = mpart[(long)pA*64 + r], mB = mpart[(long)pB*64 + r];
    const float lA = lpart[(long)pA*64 + r], lB = lpart[(long)pB*64 + r];
    const float M  = fmaxf(mA, mB);
    const float wA = __expf(mA - M), wB = __expf(mB - M);
    const float inv = 1.f / (lA*wA + lB*wB);
    const float* OA = Opart + (long)pA*4096 + r*64 + c0;
    const float* OB = Opart + (long)pB*4096 + r*64 + c0;
    const long dst = (long)b*TT*CC + (long)(qt*64 + r)*CC + h*DD + c0;
    #pragma unroll
    for (int j = 0; j < 16; j += 4) {
        float4 oa = *(const float4*)(OA + j);
        float4 ob = *(const float4*)(OB + j);
        float o0 = (oa.x*wA + ob.x*wB)*inv;
        float o1 = (oa.y*wA + ob.y*wB)*inv;
        float o2 = (oa.z*wA + ob.z*wB)*inv;
        float o3 = (oa.w*wA + ob.w*wB)*inv;
        float xs[4] = {o0, o1, o2, o3};
        s16x4 hv, lv;
        #pragma unroll
        for (int t = 0; t < 4; t++) { short hh,ll; splitbf(xs[t],hh,ll); hv[t]=hh; lv[t]=ll; }
        *(s16x4*)(aoh + dst + j) = hv;
        *(s16x4*)(aol + dst + j) = lv;
    }
}

// ---------------------------------------------------------------------------
// Column norms of sim_matrix [C, E]
// ---------------------------------------------------------------------------
__global__ __launch_bounds__(256) void colnorm_kernel(const float* __restrict__ sim,
                                                      float* __restrict__ cn) {
    const int e = blockIdx.x, tid = threadIdx.x;
    __shared__ float red[256];
    float s = 0.f;
    for (int c = tid; c < CC; c += 256) {
        float vv = sim[(long)c*EE + e];
        s += vv*vv;
    }
    red[tid] = s; __syncthreads();
    for (int st = 128; st > 0; st >>= 1) {
        if (tid < st) red[tid] += red[tid+st];
        __syncthreads();
    }
    if (tid == 0) cn[e] = sqrtf(red[0]);
}

// ---------------------------------------------------------------------------
// Router: scores, mask, k_per_token (fp32-exact). One block per token.
// ---------------------------------------------------------------------------
__global__ __launch_bounds__(256) void scores_kernel(const float* __restrict__ h2,
                                                     const float* __restrict__ sim,
                                                     const float* __restrict__ cn,
                                                     const float* __restrict__ thr,
                                                     float* __restrict__ scores,
                                                     float* __restrict__ kpt,
                                                     float* __restrict__ maskb) {
    const int row = blockIdx.x, tid = threadIdx.x;
    __shared__ float red[256*17];
    float acc[17] = {};
    for (int c = tid; c < CC; c += 256) {
        const float xv = h2[(long)row*CC + c];
        acc[16] += xv*xv;
        const float* sr = sim + (long)c*EE;
        #pragma unroll
        for (int e2 = 0; e2 < EE; e2++) acc[e2] += xv*sr[e2];
    }
    #pragma unroll
    for (int e2 = 0; e2 < 17; e2++) red[tid*17 + e2] = acc[e2];
    __syncthreads();
    for (int st = 128; st > 0; st >>= 1) {
        if (tid < st)
            for (int e2 = 0; e2 < 17; e2++) red[tid*17+e2] += red[(tid+st)*17+e2];
        __syncthreads();
    }
    if (tid < EE) {
        const float nrm = sqrtf(red[16]);
        const float sc  = red[tid] / (nrm * cn[tid]);
        scores[(long)row*EE + tid] = sc;
        const float mkv = sc > thr[0] ? 1.f : 0.f;
        maskb[(long)row*EE + tid] = mkv;
        red[tid] = mkv;
    }
    __syncthreads();
    if (tid == 0) {
        float c2 = 0.f;
        for (int e2 = 0; e2 < EE; e2++) c2 += red[e2];
        kpt[row] = c2;
    }
}

// ---------------------------------------------------------------------------
// final[n,c] = sum_e eo[n,e,c]; x_out += final, in place
// ---------------------------------------------------------------------------
__global__ __launch_bounds__(256) void moe_sum_kernel(const float* __restrict__ eo,
                                                      float* __restrict__ xio) {
    const int row = blockIdx.x, tid = threadIdx.x;
    for (int c = tid; c < CC; c += 256) {
        float s = 0.f;
        #pragma unroll
        for (int e2 = 0; e2 < EE; e2++)
            s += eo[((long)row*EE + e2)*CC + c];
        xio[(long)row*CC + c] += s;
    }
}

// ---------------------------------------------------------------------------
extern "C" void kernel_launch(void* const* d_in, const int* in_sizes, int n_in,
                              void* d_out, int out_size, void* d_ws, size_t ws_size,
                              hipStream_t stream) {
    const float* x     = (const float*)d_in[0];
    const float* ln1_g = (const float*)d_in[1];
    const float* ln1_b = (const float*)d_in[2];
    const float* ln2_g = (const float*)d_in[3];
    const float* ln2_b = (const float*)d_in[4];
    const float* wq    = (const float*)d_in[5];
    const float* wk    = (const float*)d_in[6];
    const float* wv    = (const float*)d_in[7];
    const float* wo    = (const float*)d_in[8];
    const float* sim   = (const float*)d_in[9];
    const float* thr   = (const float*)d_in[10];
    const float* w1    = (const float*)d_in[11];
    const float* w2    = (const float*)d_in[12];

    float* out_x      = (float*)d_out;
    float* out_scores = out_x + (long)NN*CC;
    float* out_eo     = out_scores + (long)NN*EE;
    float* out_kpt    = out_eo + (long)NN*EE*CC;

    const long MF = (long)NN*CC;     // 2M floats
    const long CK = (long)CC*CC;     // 1M elems per weight slab
    float* ws   = (float*)d_ws;
    float* h    = ws;                                                // LN2 fp32 (router input)
    float* qb   = ws + MF;
    float* kb   = ws + 2*MF;
    float* vb   = ws + 3*MF;
    __hip_bfloat16* aoh = (__hip_bfloat16*)(ws + 4*MF);              // 2M bf16 (attn out hi)
    __hip_bfloat16* aol = (__hip_bfloat16*)(ws + 4*MF + MF/2);       // 2M bf16 (attn out lo)
    __hip_bfloat16* h2b = (__hip_bfloat16*)(ws + 5*MF);              // 2M bf16
    float* Opart = ws + 5*MF + MF/2;                                 // 2MF floats (attn partials)
    __hip_bfloat16* hh  = (__hip_bfloat16*)(ws + 5*MF + MF/2);       // alias Opart: LN1 hi (dead before attn)
    __hip_bfloat16* hl  = (__hip_bfloat16*)(ws + 6*MF);              // alias Opart: LN1 lo
    __hip_bfloat16* mid = (__hip_bfloat16*)(ws + 5*MF + MF/2);       // alias Opart: expert mid (after merge)
    __hip_bfloat16* wsph = (__hip_bfloat16*)(ws + 7*MF + MF/2);      // [4][C][C] weight hi (QKVO)
    __hip_bfloat16* wspl = (__hip_bfloat16*)(ws + 8*MF + MF/2);      // [4][C][C] weight lo
    __hip_bfloat16* w1t  = (__hip_bfloat16*)(ws + 7*MF + MF/2);      // alias wsph (after WO GEMM)
    __hip_bfloat16* w2t  = (__hip_bfloat16*)(ws + 8*MF + MF/2);      // alias wspl
    float* maskb = ws + 9*MF + MF/2;                                  // 32K
    float* cn    = maskb + (long)NN*EE;                               // 16
    float* mpart = cn + 16;                                           // 64K
    float* lpart = mpart + 1024L*64;                                  // 64K

    // 0. one-shot QKVO weight transpose + bf16x3 split: W[K][N] -> Wt[N][K] hi/lo
    {
        dim3 gt(CC/32, CC/32, 1);
        transpose_split<<<gt, 256, 0, stream>>>(wq, wsph + 0*CK, wspl + 0*CK, CC, CC);
        transpose_split<<<gt, 256, 0, stream>>>(wk, wsph + 1*CK, wspl + 1*CK, CC, CC);
        transpose_split<<<gt, 256, 0, stream>>>(wv, wsph + 2*CK, wspl + 2*CK, CC, CC);
        transpose_split<<<gt, 256, 0, stream>>>(wo, wsph + 3*CK, wspl + 3*CK, CC, CC);
    }

    // 1. LN1 -> pre-split bf16 hi/lo (no fp32 round-trip)
    ln_kernel<<<NN, 256, 0, stream>>>(x, ln1_g, ln1_b, nullptr, nullptr, hh, hl);

    // 2. fused QKV projection (bf16x3 split MFMA, conflict-free staging)
    {
        dim3 gq(CC/128, NN/64, 3);
        gemm_split<0><<<gq, 256, 0, stream>>>(hh, hl, wsph, wspl, qb, NN, CC, CC, nullptr);
    }

    // 3. causal attention (MFMA flash, kt-split) + merge -> split bf16 ao
    {
        dim3 gattn(32, HH, BB);
        attn_split<<<gattn, 256, 0, stream>>>(qb, kb, vb, Opart, mpart, lpart);
        dim3 gmerge(16, HH, BB);
        attn_merge<<<gmerge, 256, 0, stream>>>(Opart, mpart, lpart, aoh, aol);
    }

    // 4. output projection + residual -> d_out x slot
    {
        dim3 go(CC/128, NN/64, 1);
        gemm_split<1><<<go, 256, 0, stream>>>(aoh, aol, wsph + 3*CK, wspl + 3*CK,
                                              out_x, NN, CC, CC, x);
    }

    // 4.5 expert weight transposes (now safe to overwrite the QKVO split region)
    {
        dim3 g1(II/32, CC/32, EE);
        transpose_f2b<<<g1, 256, 0, stream>>>(w1, (long)CC*II, w1t, (long)CC*II, CC, II);
        dim3 g2(CC/32, II/32, EE);
        transpose_f2b<<<g2, 256, 0, stream>>>(w2, (long)II*CC, w2t, (long)II*CC, II, CC);
    }

    // 5. LN2 -> h (fp32 for router) + h2b (bf16 for expert GEMM)
    ln_kernel<<<NN, 256, 0, stream>>>(out_x, ln2_g, ln2_b, h, h2b, nullptr, nullptr);

    // 6. router (fp32-exact so mask matches reference bit-stably)
    colnorm_kernel<<<EE, 256, 0, stream>>>(sim, cn);
    scores_kernel<<<NN, 256, 0, stream>>>(h, sim, cn, thr, out_scores, out_kpt, maskb);

    // 7. expert GEMM 1 (MFMA bf16): mid[e] = gelu(h2 @ w1[e]) -> bf16
    {
        dim3 g(II/128, NN/128, EE);
        gemm_mfma<0><<<g, 256, 0, stream>>>(h2b, 0, w1t, (long)II*CC,
                                            mid, (long)NN*II, II,
                                            NN, II, CC, nullptr);
    }

    // 8. expert GEMM 2 (MFMA bf16): eo[n,e,:] = (mid[e] @ w2[e]) * mask[n,e]
    {
        dim3 g(CC/128, NN/128, EE);
        gemm_mfma<1><<<g, 256, 0, stream>>>(mid, (long)NN*II, w2t, (long)II*CC,
                                            out_eo, (long)CC, EE*CC,
                                            NN, CC, II, maskb);
    }

    // 9. final = sum_e eo; x += final (in place on d_out)
    moe_sum_kernel<<<NN, 256, 0, stream>>>(out_eo, out_x);
}

// Round 3
// 477.841 us; speedup vs baseline: 1.5908x; 1.0331x over previous
//
#include <hip/hip_runtime.h>
#include <hip/hip_bf16.h>
#include <math.h>

// Problem constants
#define BB 2
#define TT 1024
#define CC 1024
#define HH 16
#define DD 64
#define EE 16
#define II 256
#define NN (BB*TT)          // 2048 tokens
#define EPSLN 1e-5f
#define LDA 72              // bf16 LDS row stride: 144B rows, 16B-aligned

typedef __attribute__((ext_vector_type(8))) short short8;
typedef __attribute__((ext_vector_type(4))) short s16x4;
typedef __attribute__((ext_vector_type(4))) float f32x4;

__device__ inline void splitbf(float x, short& hi, short& lo) {
    __hip_bfloat16 h = __float2bfloat16(x);
    float hf = __bfloat162float(h);
    __hip_bfloat16 l = __float2bfloat16(x - hf);
    hi = *(short*)&h;
    lo = *(short*)&l;
}

// ---------------------------------------------------------------------------
// LayerNorm: one block per row of 1024.
// Optional outputs: fp32, single bf16, split bf16 hi/lo.
// ---------------------------------------------------------------------------
__global__ __launch_bounds__(256) void ln_kernel(const float* __restrict__ x,
                                                 const float* __restrict__ g,
                                                 const float* __restrict__ bta,
                                                 float* __restrict__ out,
                                                 __hip_bfloat16* __restrict__ outb,
                                                 __hip_bfloat16* __restrict__ outh,
                                                 __hip_bfloat16* __restrict__ outl) {
    const int row = blockIdx.x, tid = threadIdx.x;
    __shared__ float r1[256], r2[256];
    const float* xr = x + (long)row * CC;
    float4 xv = ((const float4*)xr)[tid];
    float s  = xv.x + xv.y + xv.z + xv.w;
    float q2 = xv.x*xv.x + xv.y*xv.y + xv.z*xv.z + xv.w*xv.w;
    r1[tid] = s; r2[tid] = q2; __syncthreads();
    for (int st = 128; st > 0; st >>= 1) {
        if (tid < st) { r1[tid] += r1[tid+st]; r2[tid] += r2[tid+st]; }
        __syncthreads();
    }
    const float mu  = r1[0] * (1.f/CC);
    const float var = r2[0] * (1.f/CC) - mu*mu;
    const float rs  = rsqrtf(var + EPSLN);
    float4 gv = ((const float4*)g)[tid];
    float4 bv = ((const float4*)bta)[tid];
    float4 ov;
    ov.x = (xv.x-mu)*rs*gv.x + bv.x;
    ov.y = (xv.y-mu)*rs*gv.y + bv.y;
    ov.z = (xv.z-mu)*rs*gv.z + bv.z;
    ov.w = (xv.w-mu)*rs*gv.w + bv.w;
    if (out)
        ((float4*)(out + (long)row * CC))[tid] = ov;
    if (outb) {
        __hip_bfloat16* p = outb + (long)row * CC + tid*4;
        p[0] = __float2bfloat16(ov.x); p[1] = __float2bfloat16(ov.y);
        p[2] = __float2bfloat16(ov.z); p[3] = __float2bfloat16(ov.w);
    }
    if (outh) {
        float xs[4] = {ov.x, ov.y, ov.z, ov.w};
        s16x4 hv, lv;
        #pragma unroll
        for (int j = 0; j < 4; j++) { short h,l; splitbf(xs[j], h, l); hv[j]=h; lv[j]=l; }
        *(s16x4*)(outh + (long)row * CC + tid*4) = hv;
        *(s16x4*)(outl + (long)row * CC + tid*4) = lv;
    }
}

// ---------------------------------------------------------------------------
// One-shot weight prep: W[K][N] fp32 -> Wt[N][K] bf16 hi + lo (bf16x3 split).
// ---------------------------------------------------------------------------
__global__ __launch_bounds__(256) void transpose_split(const float* __restrict__ W,
                                                       __hip_bfloat16* __restrict__ Wth,
                                                       __hip_bfloat16* __restrict__ Wtl,
                                                       int K, int N) {
    const int n0 = blockIdx.x * 32, k0 = blockIdx.y * 32;
    __shared__ float t[32][33];
    const int tx = threadIdx.x & 31, ty = threadIdx.x >> 5;
    #pragma unroll
    for (int i = 0; i < 4; i++)
        t[ty + i*8][tx] = W[(long)(k0 + ty + i*8)*N + n0 + tx];
    __syncthreads();
    #pragma unroll
    for (int i = 0; i < 4; i++) {
        float v = t[tx][ty + i*8];
        short h, l; splitbf(v, h, l);
        *(short*)&Wth[(long)(n0 + ty + i*8)*K + k0 + tx] = h;
        *(short*)&Wtl[(long)(n0 + ty + i*8)*K + k0 + tx] = l;
    }
}

// ---------------------------------------------------------------------------
// bf16 transpose for V: [b*T + t][C] (hi/lo) -> [(b*H + h)*64 + d][T] (hi/lo)
// ---------------------------------------------------------------------------
__global__ __launch_bounds__(256) void transpose_v_bf16(
        const __hip_bfloat16* __restrict__ Vh, const __hip_bfloat16* __restrict__ Vl,
        __hip_bfloat16* __restrict__ Vth, __hip_bfloat16* __restrict__ Vtl) {
    const int b = blockIdx.z;
    const int c0 = blockIdx.y * 32, t0 = blockIdx.x * 32;
    __shared__ unsigned short th[32][33], tl[32][33];
    const int tx = threadIdx.x & 31, ty = threadIdx.x >> 5;
    const unsigned short* vh = (const unsigned short*)Vh;
    const unsigned short* vl = (const unsigned short*)Vl;
    #pragma unroll
    for (int i = 0; i < 4; i++) {
        const long src = ((long)b*TT + t0 + ty + i*8)*CC + c0 + tx;
        th[ty + i*8][tx] = vh[src];
        tl[ty + i*8][tx] = vl[src];
    }
    __syncthreads();
    #pragma unroll
    for (int i = 0; i < 4; i++) {
        const int gc = c0 + ty + i*8;          // global channel
        const int hh = gc >> 6, d = gc & 63;
        const long dst = ((long)(b*HH + hh)*64 + d)*TT + t0 + tx;
        ((unsigned short*)Vth)[dst] = th[tx][ty + i*8];
        ((unsigned short*)Vtl)[dst] = tl[tx][ty + i*8];
    }
}

// ---------------------------------------------------------------------------
// fp32-accurate MFMA GEMM via bf16x3 split (AhBh + AhBl + AlBh) with
// PRE-SPLIT inputs: A = (Ah,Al)[M][K] bf16, B = (Bth,Btl)[z][N][K] bf16.
// All LDS staging is contiguous short8 -> no bank-conflict scatter.
// Tile 64Mx128N, BK=32, 4 waves. z indexes weight slot + C output slab.
// EPI: 0 = fp32 out, 1 = fp32 +resid, 2 = split bf16 hi/lo out
// ---------------------------------------------------------------------------
template<int EPI>
__global__ __launch_bounds__(256, 2) void gemm_split(
        const __hip_bfloat16* __restrict__ Ah,
        const __hip_bfloat16* __restrict__ Al,
        const __hip_bfloat16* __restrict__ Bh_base,
        const __hip_bfloat16* __restrict__ Bl_base,
        float* __restrict__ C_base,
        __hip_bfloat16* __restrict__ Ch_base,
        __hip_bfloat16* __restrict__ Cl_base,
        int M, int N, int K,
        const float* __restrict__ resid) {
    __shared__ __hip_bfloat16 Ash[64][40], Asl[64][40];
    __shared__ __hip_bfloat16 Bsh[128][40], Bsl[128][40];
    const int z = blockIdx.z;
    const __hip_bfloat16* Bth = Bh_base + (long)z * N * K;
    const __hip_bfloat16* Btl = Bl_base + (long)z * N * K;
    const int n0 = blockIdx.x * 128, m0 = blockIdx.y * 64;
    const int tid = threadIdx.x;
    const int wave = tid >> 6, lane = tid & 63;
    const int wm = (wave >> 1) * 32, wn = (wave & 1) * 64;
    const int l15 = lane & 15, quad = lane >> 4;

    f32x4 acc[2][4] = {};

    for (int k0 = 0; k0 < K; k0 += 32) {
        {   // A tile: 64 rows x 32 k, contiguous short8 per thread
            const int r = tid >> 2, kg = (tid & 3) * 8;
            *(short8*)&Ash[r][kg] = *(const short8*)(Ah + (long)(m0 + r)*K + k0 + kg);
            *(short8*)&Asl[r][kg] = *(const short8*)(Al + (long)(m0 + r)*K + k0 + kg);
        }
        #pragma unroll
        for (int it = 0; it < 2; it++) {   // B tile: 128 rows x 32 k
            const int idx = tid + it*256;
            const int r = idx >> 2, kg = (idx & 3) * 8;
            *(short8*)&Bsh[r][kg] = *(const short8*)(Bth + (long)(n0 + r)*K + k0 + kg);
            *(short8*)&Bsl[r][kg] = *(const short8*)(Btl + (long)(n0 + r)*K + k0 + kg);
        }
        __syncthreads();
        short8 ah[2], al[2], bh[4], bl[4];
        #pragma unroll
        for (int mi = 0; mi < 2; mi++) {
            ah[mi] = *(const short8*)&Ash[wm + mi*16 + l15][quad*8];
            al[mi] = *(const short8*)&Asl[wm + mi*16 + l15][quad*8];
        }
        #pragma unroll
        for (int ni = 0; ni < 4; ni++) {
            bh[ni] = *(const short8*)&Bsh[wn + ni*16 + l15][quad*8];
            bl[ni] = *(const short8*)&Bsl[wn + ni*16 + l15][quad*8];
        }
        #pragma unroll
        for (int mi = 0; mi < 2; mi++)
            #pragma unroll
            for (int ni = 0; ni < 4; ni++) {
                acc[mi][ni] = __builtin_amdgcn_mfma_f32_16x16x32_bf16(ah[mi], bh[ni], acc[mi][ni], 0,0,0);
                acc[mi][ni] = __builtin_amdgcn_mfma_f32_16x16x32_bf16(ah[mi], bl[ni], acc[mi][ni], 0,0,0);
                acc[mi][ni] = __builtin_amdgcn_mfma_f32_16x16x32_bf16(al[mi], bh[ni], acc[mi][ni], 0,0,0);
            }
        __syncthreads();
    }

    #pragma unroll
    for (int mi = 0; mi < 2; mi++)
        #pragma unroll
        for (int r = 0; r < 4; r++) {
            const int row = m0 + wm + mi*16 + quad*4 + r;
            #pragma unroll
            for (int ni = 0; ni < 4; ni++) {
                const int col = n0 + wn + ni*16 + l15;
                float val = acc[mi][ni][r];
                if (EPI == 2) {
                    short hh, ll; splitbf(val, hh, ll);
                    *(short*)&Ch_base[(long)z*M*N + (long)row*N + col] = hh;
                    *(short*)&Cl_base[(long)z*M*N + (long)row*N + col] = ll;
                } else {
                    if (EPI == 1) val += resid[(long)row*N + col];
                    C_base[(long)z*M*N + (long)row*N + col] = val;
                }
            }
        }
}

// ---------------------------------------------------------------------------
// bf16 MFMA GEMM (expert path): C = A[M,K] * Bt[N,K]^T, batched over z.
// EPI: 0 = exact gelu -> bf16 out; 1 = *mask -> fp32 strided out
// ---------------------------------------------------------------------------
template<int EPI>
__global__ __launch_bounds__(256) void gemm_mfma(
        const __hip_bfloat16* __restrict__ A, long sAe,
        const __hip_bfloat16* __restrict__ Bt, long sBe,
        void* __restrict__ Cp, long sCe, int ldc,
        int M, int N, int K,
        const float* __restrict__ mask) {
    constexpr int LDK = 40;
    __shared__ __hip_bfloat16 As[128][LDK];
    __shared__ __hip_bfloat16 Bs[128][LDK];
    const int e = blockIdx.z;
    A  += (long)e * sAe;
    Bt += (long)e * sBe;
    const int n0 = blockIdx.x * 128, m0 = blockIdx.y * 128;
    const int tid = threadIdx.x;
    const int wave = tid >> 6, lane = tid & 63;
    const int wm = (wave >> 1) * 64, wn = (wave & 1) * 64;
    const int l15 = lane & 15, quad = lane >> 4;

    f32x4 acc[4][4] = {};

    for (int k0 = 0; k0 < K; k0 += 32) {
        #pragma unroll
        for (int it = 0; it < 2; it++) {
            int idx = tid + it*256;
            int r = idx >> 2, kg = idx & 3;
            short8 av = *(const short8*)(A  + (long)(m0 + r)*K + k0 + kg*8);
            short8 bv = *(const short8*)(Bt + (long)(n0 + r)*K + k0 + kg*8);
            *(short8*)&As[r][kg*8] = av;
            *(short8*)&Bs[r][kg*8] = bv;
        }
        __syncthreads();
        short8 af[4], bff[4];
        #pragma unroll
        for (int i = 0; i < 4; i++) {
            af[i]  = *(const short8*)&As[wm + i*16 + l15][quad*8];
            bff[i] = *(const short8*)&Bs[wn + i*16 + l15][quad*8];
        }
        #pragma unroll
        for (int mi = 0; mi < 4; mi++)
            #pragma unroll
            for (int ni = 0; ni < 4; ni++)
                acc[mi][ni] = __builtin_amdgcn_mfma_f32_16x16x32_bf16(
                                  af[mi], bff[ni], acc[mi][ni], 0, 0, 0);
        __syncthreads();
    }

    #pragma unroll
    for (int mi = 0; mi < 4; mi++) {
        #pragma unroll
        for (int r = 0; r < 4; r++) {
            const int row = m0 + wm + mi*16 + quad*4 + r;
            float mv = 0.f;
            if (EPI == 1) mv = mask[(long)row*EE + e];
            #pragma unroll
            for (int ni = 0; ni < 4; ni++) {
                const int col = n0 + wn + ni*16 + l15;
                float val = acc[mi][ni][r];
                if (EPI == 0) {
                    val = 0.5f*val*(1.f + erff(val*0.70710678118f));
                    ((__hip_bfloat16*)Cp)[(long)e*sCe + (long)row*ldc + col] =
                        __float2bfloat16(val);
                } else {
                    ((float*)Cp)[(long)e*sCe + (long)row*ldc + col] = val*mv;
                }
            }
        }
    }
}

// ---------------------------------------------------------------------------
// Tiled fp32 -> bf16 transpose for expert weights.
// ---------------------------------------------------------------------------
__global__ __launch_bounds__(256) void transpose_f2b(const float* __restrict__ W, long sWe,
                                                     __hip_bfloat16* __restrict__ Wt, long sWte,
                                                     int K, int N) {
    const int e = blockIdx.z;
    W  += (long)e * sWe;
    Wt += (long)e * sWte;
    const int n0 = blockIdx.x * 32, k0 = blockIdx.y * 32;
    __shared__ float t[32][33];
    const int tx = threadIdx.x & 31, ty = threadIdx.x >> 5;
    #pragma unroll
    for (int i = 0; i < 4; i++)
        t[ty + i*8][tx] = W[(long)(k0 + ty + i*8)*N + n0 + tx];
    __syncthreads();
    #pragma unroll
    for (int i = 0; i < 4; i++)
        Wt[(long)(n0 + ty + i*8)*K + k0 + tx] = __float2bfloat16(t[tx][ty + i*8]);
}

// ---------------------------------------------------------------------------
// Flash attention with bf16x3 MFMA for QK^T and PV. kt-split for balance.
// Block = (b, h, qt, half). All inputs PRE-SPLIT bf16 hi/lo:
//   Q,K [token][C] (head slab at h*64); V pre-transposed [(b*H+h)*64+d][T].
// Staging is pure contiguous short8 copies (no conversion, no scatter).
// P overwrites K region (C/D -> A layout round-trip). Online softmax in
// registers via width-16 shuffles. Unnormalized O + (m,l) partials out.
// ---------------------------------------------------------------------------
__global__ __launch_bounds__(256, 4) void attn_split(
        const __hip_bfloat16* __restrict__ Qh, const __hip_bfloat16* __restrict__ Ql,
        const __hip_bfloat16* __restrict__ Kh, const __hip_bfloat16* __restrict__ Kl,
        const __hip_bfloat16* __restrict__ Vtg_h, const __hip_bfloat16* __restrict__ Vtg_l,
        float* __restrict__ Opart,
        float* __restrict__ mpart,
        float* __restrict__ lpart) {
    __shared__ __hip_bfloat16 KPh[64][LDA], KPl[64][LDA];   // K, then P
    __shared__ __hip_bfloat16 Vth[64][LDA], Vtl[64][LDA];   // V^T [d][kk]

    const int bx = blockIdx.x;                 // 0..31, heavy qt first
    const int qt = 15 - (bx >> 1), half = bx & 1;
    const int h = blockIdx.y, b = blockIdx.z;
    const int tid = threadIdx.x;
    const int wave = tid >> 6, lane = tid & 63;
    const int l15 = lane & 15, quad = lane >> 4;
    const int wm = wave * 16;                  // wave's 16 q-rows in the 64-tile
    const long tbase = (long)b * TT * CC + (long)h * DD;          // [token][C] slab
    const long vbase = (long)(b*HH + h) * 64 * TT;                // V^T slab
    const int pidx = ((b*HH + h)*16 + qt)*2 + half;
    float* Op = Opart + (long)pidx * 4096;

    const int n_kt = qt + 1, mid_kt = (n_kt + 1) >> 1;
    const int kt_lo = half ? mid_kt : 0;
    const int kt_hi = half ? n_kt   : mid_kt;

    if (kt_lo >= kt_hi) {      // empty half (qt=0): neutral partials
        for (int i = tid; i < 64*64; i += 256) Op[i] = 0.f;
        if (tid < 64) { mpart[(long)pidx*64 + tid] = -1e30f; lpart[(long)pidx*64 + tid] = 0.f; }
        return;
    }

    // Q A-fragments direct from pre-split global: row = qt*64+wm+l15, k = kc*32+quad*8
    short8 qh[2], ql[2];
    {
        const long qoff = tbase + (long)(qt*64 + wm + l15)*CC;
        #pragma unroll
        for (int kc = 0; kc < 2; kc++) {
            qh[kc] = *(const short8*)(Qh + qoff + kc*32 + quad*8);
            ql[kc] = *(const short8*)(Ql + qoff + kc*32 + quad*8);
        }
    }

    f32x4 oacc[4] = {};            // 4 d-tiles, rows = quad*4+reg
    float m_run[4], l_run[4];
    #pragma unroll
    for (int r = 0; r < 4; r++) { m_run[r] = -1e30f; l_run[r] = 0.f; }

    for (int kt = kt_lo; kt < kt_hi; kt++) {
        __syncthreads();           // prev-iter PV reads of KP/Vt done
        // stage K rows + V^T rows: pure contiguous short8 copies
        #pragma unroll
        for (int it = 0; it < 2; it++) {
            const int idx = tid + it*256;
            const int r = idx >> 3, g = (idx & 7)*8;
            const long koff = tbase + (long)(kt*64 + r)*CC + g;
            const long voff = vbase + (long)r*TT + kt*64 + g;
            *(short8*)&KPh[r][g] = *(const short8*)(Kh + koff);
            *(short8*)&KPl[r][g] = *(const short8*)(Kl + koff);
            *(short8*)&Vth[r][g] = *(const short8*)(Vtg_h + voff);
            *(short8*)&Vtl[r][g] = *(const short8*)(Vtg_l + voff);
        }
        __syncthreads();

        // QK^T via MFMA: 4 key-tiles x 2 k-chunks x 3 split terms
        f32x4 s[4] = {};
        #pragma unroll
        for (int nt = 0; nt < 4; nt++)
            #pragma unroll
            for (int kc = 0; kc < 2; kc++) {
                short8 bh = *(const short8*)&KPh[nt*16 + l15][kc*32 + quad*8];
                short8 bl = *(const short8*)&KPl[nt*16 + l15][kc*32 + quad*8];
                s[nt] = __builtin_amdgcn_mfma_f32_16x16x32_bf16(qh[kc], bh, s[nt], 0,0,0);
                s[nt] = __builtin_amdgcn_mfma_f32_16x16x32_bf16(qh[kc], bl, s[nt], 0,0,0);
                s[nt] = __builtin_amdgcn_mfma_f32_16x16x32_bf16(ql[kc], bh, s[nt], 0,0,0);
            }

        // online softmax in regs; row = wm + quad*4 + r, col = nt*16 + l15
        const bool diag = (kt == qt);
        float alpha[4];
        float pr[4][4];
        #pragma unroll
        for (int r = 0; r < 4; r++) {
            const int rowg = wm + quad*4 + r;
            float sv[4], mx = -1e30f;
            #pragma unroll
            for (int nt = 0; nt < 4; nt++) {
                float val = s[nt][r] * 0.125f;
                if (diag && (nt*16 + l15) > rowg) val = -1e30f;
                sv[nt] = val;
                mx = fmaxf(mx, val);
            }
            #pragma unroll
            for (int off = 1; off < 16; off <<= 1) mx = fmaxf(mx, __shfl_xor(mx, off, 16));
            const float mnew = fmaxf(m_run[r], mx);
            alpha[r] = __expf(m_run[r] - mnew);
            float rs = 0.f;
            #pragma unroll
            for (int nt = 0; nt < 4; nt++) {
                float p = __expf(sv[nt] - mnew);
                pr[r][nt] = p;
                rs += p;
            }
            #pragma unroll
            for (int off = 1; off < 16; off <<= 1) rs += __shfl_xor(rs, off, 16);
            l_run[r] = l_run[r]*alpha[r] + rs;
            m_run[r] = mnew;
        }
        __syncthreads();           // all QK reads of KP done -> overwrite as P

        // write P split into KP region: row = wm+quad*4+r, col = nt*16+l15
        #pragma unroll
        for (int r = 0; r < 4; r++)
            #pragma unroll
            for (int nt = 0; nt < 4; nt++) {
                short hh, ll; splitbf(pr[r][nt], hh, ll);
                *(short*)&KPh[wm + quad*4 + r][nt*16 + l15] = hh;
                *(short*)&KPl[wm + quad*4 + r][nt*16 + l15] = ll;
            }
        // no barrier: PV reads only this wave's own 16 P-rows

        // rescale O and accumulate PV via MFMA
        #pragma unroll
        for (int dt = 0; dt < 4; dt++)
            #pragma unroll
            for (int r = 0; r < 4; r++)
                oacc[dt][r] *= alpha[r];
        #pragma unroll
        for (int kc = 0; kc < 2; kc++) {
            short8 ph = *(const short8*)&KPh[wm + l15][kc*32 + quad*8];
            short8 pl = *(const short8*)&KPl[wm + l15][kc*32 + quad*8];
            #pragma unroll
            for (int dt = 0; dt < 4; dt++) {
                short8 vh = *(const short8*)&Vth[dt*16 + l15][kc*32 + quad*8];
                short8 vl = *(const short8*)&Vtl[dt*16 + l15][kc*32 + quad*8];
                oacc[dt] = __builtin_amdgcn_mfma_f32_16x16x32_bf16(ph, vh, oacc[dt], 0,0,0);
                oacc[dt] = __builtin_amdgcn_mfma_f32_16x16x32_bf16(ph, vl, oacc[dt], 0,0,0);
                oacc[dt] = __builtin_amdgcn_mfma_f32_16x16x32_bf16(pl, vh, oacc[dt], 0,0,0);
            }
        }
    }

    // store unnormalized O partial + (m,l)
    #pragma unroll
    for (int dt = 0; dt < 4; dt++)
        #pragma unroll
        for (int r = 0; r < 4; r++)
            Op[(wm + quad*4 + r)*64 + dt*16 + l15] = oacc[dt][r];
    if (l15 == 0) {
        #pragma unroll
        for (int r = 0; r < 4; r++) {
            mpart[(long)pidx*64 + wm + quad*4 + r] = m_run[r];
            lpart[(long)pidx*64 + wm + quad*4 + r] = l_run[r];
        }
    }
}

// ---------------------------------------------------------------------------
// Merge the two kt-half partials -> normalized attention output, emitted as
// pre-split bf16 hi/lo (direct feed for the WO bf16x3 GEMM).
// ---------------------------------------------------------------------------
__global__ __launch_bounds__(256) void attn_merge(const float* __restrict__ Opart,
                                                  const float* __restrict__ mpart,
                                                  const float* __restrict__ lpart,
                                                  __hip_bfloat16* __restrict__ aoh,
                                                  __hip_bfloat16* __restrict__ aol) {
    const int qt = blockIdx.x, h = blockIdx.y, b = blockIdx.z;
    const int pA = ((b*HH + h)*16 + qt)*2, pB = pA + 1;
    const int tid = threadIdx.x;
    const int r = tid >> 2, c0 = (tid & 3) * 16;
    const float mA = mpart[(long)pA*64 + r], mB = mpart[(long)pB*64 + r];
    const float lA = lpart[(long)pA*64 + r], lB = lpart[(long)pB*64 + r];
    const float M  = fmaxf(mA, mB);
    const float wA = __expf(mA - M), wB = __expf(mB - M);
    const float inv = 1.f / (lA*wA + lB*wB);
    const float* OA = Opart + (long)pA*4096 + r*64 + c0;
    const float* OB = Opart + (long)pB*4096 + r*64 + c0;
    const long dst = (long)b*TT*CC + (long)(qt*64 + r)*CC + h*DD + c0;
    #pragma unroll
    for (int j = 0; j < 16; j += 4) {
        float4 oa = *(const float4*)(OA + j);
        float4 ob = *(const float4*)(OB + j);
        float o0 = (oa.x*wA + ob.x*wB)*inv;
        float o1 = (oa.y*wA + ob.y*wB)*inv;
        float o2 = (oa.z*wA + ob.z*wB)*inv;
        float o3 = (oa.w*wA + ob.w*wB)*inv;
        float xs[4] = {o0, o1, o2, o3};
        s16x4 hv, lv;
        #pragma unroll
        for (int t = 0; t < 4; t++) { short hh,ll; splitbf(xs[t],hh,ll); hv[t]=hh; lv[t]=ll; }
        *(s16x4*)(aoh + dst + j) = hv;
        *(s16x4*)(aol + dst + j) = lv;
    }
}

// ---------------------------------------------------------------------------
// Column norms of sim_matrix [C, E]
// ---------------------------------------------------------------------------
__global__ __launch_bounds__(256) void colnorm_kernel(const float* __restrict__ sim,
                                                      float* __restrict__ cn) {
    const int e = blockIdx.x, tid = threadIdx.x;
    __shared__ float red[256];
    float s = 0.f;
    for (int c = tid; c < CC; c += 256) {
        float vv = sim[(long)c*EE + e];
        s += vv*vv;
    }
    red[tid] = s; __syncthreads();
    for (int st = 128; st > 0; st >>= 1) {
        if (tid < st) red[tid] += red[tid+st];
        __syncthreads();
    }
    if (tid == 0) cn[e] = sqrtf(red[0]);
}

// ---------------------------------------------------------------------------
// Router: scores, mask, k_per_token (fp32-exact). One block per token.
// ---------------------------------------------------------------------------
__global__ __launch_bounds__(256) void scores_kernel(const float* __restrict__ h2,
                                                     const float* __restrict__ sim,
                                                     const float* __restrict__ cn,
                                                     const float* __restrict__ thr,
                                                     float* __restrict__ scores,
                                                     float* __restrict__ kpt,
                                                     float* __restrict__ maskb) {
    const int row = blockIdx.x, tid = threadIdx.x;
    __shared__ float red[256*17];
    float acc[17] = {};
    for (int c = tid; c < CC; c += 256) {
        const float xv = h2[(long)row*CC + c];
        acc[16] += xv*xv;
        const float* sr = sim + (long)c*EE;
        #pragma unroll
        for (int e2 = 0; e2 < EE; e2++) acc[e2] += xv*sr[e2];
    }
    #pragma unroll
    for (int e2 = 0; e2 < 17; e2++) red[tid*17 + e2] = acc[e2];
    __syncthreads();
    for (int st = 128; st > 0; st >>= 1) {
        if (tid < st)
            for (int e2 = 0; e2 < 17; e2++) red[tid*17+e2] += red[(tid+st)*17+e2];
        __syncthreads();
    }
    if (tid < EE) {
        const float nrm = sqrtf(red[16]);
        const float sc  = red[tid] / (nrm * cn[tid]);
        scores[(long)row*EE + tid] = sc;
        const float mkv = sc > thr[0] ? 1.f : 0.f;
        maskb[(long)row*EE + tid] = mkv;
        red[tid] = mkv;
    }
    __syncthreads();
    if (tid == 0) {
        float c2 = 0.f;
        for (int e2 = 0; e2 < EE; e2++) c2 += red[e2];
        kpt[row] = c2;
    }
}

// ---------------------------------------------------------------------------
// final[n,c] = sum_e eo[n,e,c]; x_out += final, in place
// ---------------------------------------------------------------------------
__global__ __launch_bounds__(256) void moe_sum_kernel(const float* __restrict__ eo,
                                                      float* __restrict__ xio) {
    const int row = blockIdx.x, tid = threadIdx.x;
    for (int c = tid; c < CC; c += 256) {
        float s = 0.f;
        #pragma unroll
        for (int e2 = 0; e2 < EE; e2++)
            s += eo[((long)row*EE + e2)*CC + c];
        xio[(long)row*CC + c] += s;
    }
}

// ---------------------------------------------------------------------------
extern "C" void kernel_launch(void* const* d_in, const int* in_sizes, int n_in,
                              void* d_out, int out_size, void* d_ws, size_t ws_size,
                              hipStream_t stream) {
    const float* x     = (const float*)d_in[0];
    const float* ln1_g = (const float*)d_in[1];
    const float* ln1_b = (const float*)d_in[2];
    const float* ln2_g = (const float*)d_in[3];
    const float* ln2_b = (const float*)d_in[4];
    const float* wq    = (const float*)d_in[5];
    const float* wk    = (const float*)d_in[6];
    const float* wv    = (const float*)d_in[7];
    const float* wo    = (const float*)d_in[8];
    const float* sim   = (const float*)d_in[9];
    const float* thr   = (const float*)d_in[10];
    const float* w1    = (const float*)d_in[11];
    const float* w2    = (const float*)d_in[12];

    float* out_x      = (float*)d_out;
    float* out_scores = out_x + (long)NN*CC;
    float* out_eo     = out_scores + (long)NN*EE;
    float* out_kpt    = out_eo + (long)NN*EE*CC;

    const long MF = (long)NN*CC;     // 2M floats
    const long CK = (long)CC*CC;     // 1M elems per weight slab
    float* ws   = (float*)d_ws;
    // [0, MF): LN2 fp32 router input; aoh/aol alias (dead before LN2 writes)
    float* h = ws;
    __hip_bfloat16* aoh = (__hip_bfloat16*)ws;                       // [0, MF/2)
    __hip_bfloat16* aol = (__hip_bfloat16*)(ws + MF/2);              // [MF/2, MF)
    // [MF, 4MF): QKV pre-split bf16 (3 slabs hi, 3 slabs lo)
    __hip_bfloat16* qkvh = (__hip_bfloat16*)(ws + MF);               // 3*NN*CC bf16
    __hip_bfloat16* qkvl = (__hip_bfloat16*)(ws + MF + 3*MF/2);
    // [4MF, 5MF): V^T pre-split bf16
    __hip_bfloat16* vth = (__hip_bfloat16*)(ws + 4*MF);
    __hip_bfloat16* vtl = (__hip_bfloat16*)(ws + 4*MF + MF/2);
    // [5MF, 5.5MF): LN2 bf16 for expert GEMM
    __hip_bfloat16* h2b = (__hip_bfloat16*)(ws + 5*MF);
    // [5.5MF, 7.5MF): attn partials; hh/hl (LN1 split) + mid alias
    float* Opart = ws + 5*MF + MF/2;
    __hip_bfloat16* hh  = (__hip_bfloat16*)(ws + 5*MF + MF/2);       // dead after QKV GEMM
    __hip_bfloat16* hl  = (__hip_bfloat16*)(ws + 6*MF);
    __hip_bfloat16* mid = (__hip_bfloat16*)(ws + 5*MF + MF/2);       // after merge
    // [7.5MF, 9.5MF): QKVO weight splits; w1t/w2t alias (after WO GEMM)
    __hip_bfloat16* wsph = (__hip_bfloat16*)(ws + 7*MF + MF/2);      // [4][C][C] hi
    __hip_bfloat16* wspl = (__hip_bfloat16*)(ws + 8*MF + MF/2);      // [4][C][C] lo
    __hip_bfloat16* w1t  = (__hip_bfloat16*)(ws + 7*MF + MF/2);
    __hip_bfloat16* w2t  = (__hip_bfloat16*)(ws + 8*MF + MF/2);
    float* maskb = ws + 9*MF + MF/2;                                  // 32K
    float* cn    = maskb + (long)NN*EE;                               // 16
    float* mpart = cn + 16;                                           // 64K
    float* lpart = mpart + 1024L*64;                                  // 64K

    // 0. one-shot QKVO weight transpose + bf16x3 split: W[K][N] -> Wt[N][K] hi/lo
    {
        dim3 gt(CC/32, CC/32, 1);
        transpose_split<<<gt, 256, 0, stream>>>(wq, wsph + 0*CK, wspl + 0*CK, CC, CC);
        transpose_split<<<gt, 256, 0, stream>>>(wk, wsph + 1*CK, wspl + 1*CK, CC, CC);
        transpose_split<<<gt, 256, 0, stream>>>(wv, wsph + 2*CK, wspl + 2*CK, CC, CC);
        transpose_split<<<gt, 256, 0, stream>>>(wo, wsph + 3*CK, wspl + 3*CK, CC, CC);
    }

    // 1. LN1 -> pre-split bf16 hi/lo (no fp32 round-trip)
    ln_kernel<<<NN, 256, 0, stream>>>(x, ln1_g, ln1_b, nullptr, nullptr, hh, hl);

    // 2. fused QKV projection -> pre-split bf16 hi/lo outputs (EPI=2)
    {
        dim3 gq(CC/128, NN/64, 3);
        gemm_split<2><<<gq, 256, 0, stream>>>(hh, hl, wsph, wspl,
                                              nullptr, qkvh, qkvl,
                                              NN, CC, CC, nullptr);
    }

    // 2.5 V transpose (bf16 hi/lo): [token][C] -> per-(b,h) [d][T]
    {
        dim3 gv(TT/32, CC/32, BB);
        transpose_v_bf16<<<gv, 256, 0, stream>>>(qkvh + 2*(long)NN*CC, qkvl + 2*(long)NN*CC,
                                                 vth, vtl);
    }

    // 3. causal attention (MFMA flash, kt-split, pre-split inputs) + merge
    {
        dim3 gattn(32, HH, BB);
        attn_split<<<gattn, 256, 0, stream>>>(qkvh, qkvl,
                                              qkvh + (long)NN*CC, qkvl + (long)NN*CC,
                                              vth, vtl, Opart, mpart, lpart);
        dim3 gmerge(16, HH, BB);
        attn_merge<<<gmerge, 256, 0, stream>>>(Opart, mpart, lpart, aoh, aol);
    }

    // 4. output projection + residual -> d_out x slot (EPI=1, fp32 out)
    {
        dim3 go(CC/128, NN/64, 1);
        gemm_split<1><<<go, 256, 0, stream>>>(aoh, aol, wsph + 3*CK, wspl + 3*CK,
                                              out_x, nullptr, nullptr,
                                              NN, CC, CC, x);
    }

    // 4.5 expert weight transposes (now safe to overwrite the QKVO split region)
    {
        dim3 g1(II/32, CC/32, EE);
        transpose_f2b<<<g1, 256, 0, stream>>>(w1, (long)CC*II, w1t, (long)CC*II, CC, II);
        dim3 g2(CC/32, II/32, EE);
        transpose_f2b<<<g2, 256, 0, stream>>>(w2, (long)II*CC, w2t, (long)II*CC, II, CC);
    }

    // 5. LN2 -> h (fp32 for router) + h2b (bf16 for expert GEMM)
    ln_kernel<<<NN, 256, 0, stream>>>(out_x, ln2_g, ln2_b, h, h2b, nullptr, nullptr);

    // 6. router (fp32-exact so mask matches reference bit-stably)
    colnorm_kernel<<<EE, 256, 0, stream>>>(sim, cn);
    scores_kernel<<<NN, 256, 0, stream>>>(h, sim, cn, thr, out_scores, out_kpt, maskb);

    // 7. expert GEMM 1 (MFMA bf16): mid[e] = gelu(h2 @ w1[e]) -> bf16
    {
        dim3 g(II/128, NN/128, EE);
        gemm_mfma<0><<<g, 256, 0, stream>>>(h2b, 0, w1t, (long)II*CC,
                                            mid, (long)NN*II, II,
                                            NN, II, CC, nullptr);
    }

    // 8. expert GEMM 2 (MFMA bf16): eo[n,e,:] = (mid[e] @ w2[e]) * mask[n,e]
    {
        dim3 g(CC/128, NN/128, EE);
        gemm_mfma<1><<<g, 256, 0, stream>>>(mid, (long)NN*II, w2t, (long)II*CC,
                                            out_eo, (long)CC, EE*CC,
                                            NN, CC, II, maskb);
    }

    // 9. final = sum_e eo; x += final (in place on d_out)
    moe_sum_kernel<<<NN, 256, 0, stream>>>(out_eo, out_x);
}